// Round 12
// baseline (247.184 us; speedup 1.0000x reference)
//
#include <hip/hip_runtime.h>
#include <hip/hip_bf16.h>

typedef __attribute__((ext_vector_type(8))) short short8;
typedef __attribute__((ext_vector_type(4))) float f32x4;

#define B_   16
#define O_   512
#define C_   512
#define T_   4096
#define TP   (T_ + 32)     // padded t extent: 16 zero rows each side
#define KT   5
#define BM   128
#define BN   512
#define BK   32
#define NCHUNK (C_/BK)
#define AFR  40            // A fragments: 5 taps x 8 rowblocks, 1024B each
#define BGR  33            // B row-groups: 33 x 16 rows x 64B

__device__ __forceinline__ void gload_lds16(const void* g, void* l) {
    __builtin_amdgcn_global_load_lds(
        (const __attribute__((address_space(1))) unsigned int*)g,
        (__attribute__((address_space(3))) unsigned int*)l, 16, 0, 0);
}

// ---------------- fused prep: wrepack (blocks 0..5119) + padzero (5120..6143) ----
__global__ void prep_kernel(const float* __restrict__ w,
                            unsigned short* __restrict__ wb,
                            unsigned short* __restrict__ xt) {
    int bid = blockIdx.x;
    if (bid < 5120) {
        int e   = bid * 256 + threadIdx.x;
        int n   = e / (O_ * C_);
        int rem = e % (O_ * C_);
        int o   = rem / C_;
        int c   = rem % C_;
        float v = w[((size_t)o * C_ + c) * KT + n];
        __hip_bfloat16 h = __float2bfloat16(v);
        wb[e] = *reinterpret_cast<unsigned short*>(&h);
    } else {
        int i = (bid - 5120) * 256 + threadIdx.x;
        int b = i / (32 * C_);
        int r = (i / C_) % 32;
        int c = i % C_;
        int tp = (r < 16) ? r : (T_ + r);
        xt[((size_t)b * TP + tp) * C_ + c] = 0;
    }
}

// ---------------- x transpose: x[b][c][t] f32 -> xT[b][16+t][c] bf16 ----------------
__global__ void xtrans_kernel(const float* __restrict__ x, unsigned short* __restrict__ xt) {
    __shared__ float tile[64][65];
    int b  = blockIdx.z;
    int c0 = blockIdx.y * 64;
    int t0 = blockIdx.x * 64;
    const float* xb = x + ((size_t)b * C_ + c0) * T_ + t0;
#pragma unroll
    for (int p = 0; p < 4; ++p) {
        int idx = p * 256 + threadIdx.x;
        int cl = idx >> 4;
        int tj = (idx & 15) << 2;
        float4 v = *reinterpret_cast<const float4*>(xb + (size_t)cl * T_ + tj);
        tile[cl][tj + 0] = v.x;
        tile[cl][tj + 1] = v.y;
        tile[cl][tj + 2] = v.z;
        tile[cl][tj + 3] = v.w;
    }
    __syncthreads();
    unsigned short* xtb = xt + ((size_t)b * TP + 16 + t0) * C_ + c0;
#pragma unroll
    for (int p = 0; p < 2; ++p) {
        int g  = p * 256 + threadIdx.x;
        int tl = g >> 3;
        int cj = (g & 7) << 3;
        unsigned short tmp[8];
#pragma unroll
        for (int i = 0; i < 8; ++i) {
            __hip_bfloat16 h = __float2bfloat16(tile[cj + i][tl]);
            tmp[i] = *reinterpret_cast<unsigned short*>(&h);
        }
        *reinterpret_cast<short8*>(xtb + (size_t)tl * C_ + cj) =
            *reinterpret_cast<const short8*>(tmp);
    }
}

// ---------------- conv-as-GEMM, register-pipelined phases + barriers ----------------
// Block tile 128(o) x 512(t), BK=32, 8 waves, wave tile 128x64 (1M x 8N).
// Phase n: {LDB(tap n); LDA(tap n+1 -> other reg set); gloads; s_barrier;
//           sched_barrier; setprio; 32 MFMA(tap n)}.
// The af-next ds_reads execute on the LDS pipe WHILE the matrix pipe runs tap n's
// MFMAs (compiler emits counted lgkm: drains bf only, leaves af-next in flight).
// Chunk boundary (ph4): vmcnt(0)+BAR, then tap0' ds-read from the fresh buffer,
// lgkmcnt(8)+sched_barrier (rule 18) + BAR makes next-chunk gloads WAR-safe.
#define BARR __builtin_amdgcn_s_barrier()
#define SB0  __builtin_amdgcn_sched_barrier(0)

#define LDB(TAP, BUF)                                                       \
    _Pragma("unroll")                                                       \
    for (int ni = 0; ni < 4; ++ni) {                                        \
        int row = rb + (ni * 16 - (TAP));                                   \
        int off = row * 32 + ((lg ^ ((row >> 1) & 3)) << 3);                \
        bf[ni] = *reinterpret_cast<const short8*>(&b_lds[BUF][off]);        \
    }

#define LDA(SET, TAP, BUF)                                                  \
    _Pragma("unroll")                                                       \
    for (int mi = 0; mi < 8; ++mi)                                          \
        af[SET][mi] = *reinterpret_cast<const short8*>(                     \
            &a_lds[BUF][((TAP) * 8 + mi) * 512 + lane * 8]);

#define MFMAS(SET)                                                          \
    __builtin_amdgcn_s_setprio(1);                                          \
    _Pragma("unroll")                                                       \
    for (int mi = 0; mi < 8; ++mi)                                          \
        _Pragma("unroll")                                                   \
        for (int ni = 0; ni < 4; ++ni)                                      \
            acc[mi][ni] = __builtin_amdgcn_mfma_f32_16x16x32_bf16(          \
                af[SET][mi], bf[ni], acc[mi][ni], 0, 0, 0);                 \
    __builtin_amdgcn_s_setprio(0);

#define GLA(K, DB) gload_lds16(ag + (size_t)((K) * O_ + wid * 16) * C_ + c1,   \
                               &a_lds[DB][((K) * 8 + wid) * 512])
#define GLB(J, DB) gload_lds16(bg + (size_t)((J) * 16) * C_ + c1,              \
                               &b_lds[DB][(J) * 512])

#define CHUNK_BODY(CH, PAR)                                                    \
    {                                                                          \
        int c1  = ((CH) + 1) * BK;                                             \
        bool pf = ((CH) + 1 < NCHUNK);                                         \
        /* ph0 */                                                              \
        LDB(0, PAR); LDA((1 + PAR) & 1, 1, PAR);                               \
        if (pf) { GLA(0, (PAR) ^ 1); GLA(1, (PAR) ^ 1); GLB(wid, (PAR) ^ 1); } \
        BARR; SB0; MFMAS((0 + PAR) & 1);                                       \
        /* ph1 */                                                              \
        LDB(1, PAR); LDA((2 + PAR) & 1, 2, PAR);                               \
        if (pf) { GLA(2, (PAR) ^ 1); GLA(3, (PAR) ^ 1); GLB(8 + wid, (PAR) ^ 1); } \
        BARR; SB0; MFMAS((1 + PAR) & 1);                                       \
        /* ph2 */                                                              \
        LDB(2, PAR); LDA((3 + PAR) & 1, 3, PAR);                               \
        if (pf) { GLA(4, (PAR) ^ 1); GLB(16 + wid, (PAR) ^ 1); GLB(24 + wid, (PAR) ^ 1); } \
        BARR; SB0; MFMAS((2 + PAR) & 1);                                       \
        /* ph3 */                                                              \
        LDB(3, PAR); LDA((4 + PAR) & 1, 4, PAR);                               \
        if (pf && wid == 0) GLB(32, (PAR) ^ 1);                                \
        BARR; SB0; MFMAS((3 + PAR) & 1);                                       \
        /* ph4: chunk boundary */                                              \
        if (pf) {                                                              \
            asm volatile("s_waitcnt vmcnt(0)" ::: "memory");                   \
            BARR; SB0;                                                         \
            LDB(4, PAR); LDA((5 + PAR) & 1, 0, (PAR) ^ 1);                     \
            asm volatile("s_waitcnt lgkmcnt(8)" ::: "memory"); SB0;            \
            BARR; SB0;                                                         \
        } else {                                                               \
            LDB(4, PAR);                                                       \
        }                                                                      \
        MFMAS((4 + PAR) & 1);                                                  \
    }

__global__ __launch_bounds__(512, 2) void conv_gemm_kernel(
        const unsigned short* __restrict__ wb,
        const unsigned short* __restrict__ xt,
        const float* __restrict__ bias,
        float* __restrict__ out) {
    __shared__ unsigned short a_lds[2][AFR * 512];   // 2 x 40960 B
    __shared__ unsigned short b_lds[2][BGR * 512];   // 2 x 33792 B

    // XCD-aware bijective swizzle (512 blocks): o-tile innermost.
    int bid = blockIdx.x;
    int swz = (bid & 7) * 64 + (bid >> 3);
    int o0  = (swz & 3) * BM;
    int t0  = ((swz >> 2) & 7) * BN;
    int b   = swz >> 5;

    int tid  = threadIdx.x;
    int lane = tid & 63;
    int wid  = tid >> 6;       // 0..7 = wave n-position
    int lr   = lane & 15;
    int lg   = lane >> 4;
    int rb   = wid * 64 + lr + 4;   // B row base (tap 0, ni 0)

    f32x4 acc[8][4];
#pragma unroll
    for (int mi = 0; mi < 8; ++mi)
#pragma unroll
        for (int ni = 0; ni < 4; ++ni)
            acc[mi][ni] = (f32x4)0.0f;

    // per-lane global staging bases
    const unsigned short* ag = wb + (size_t)(o0 + lr) * C_ + lg * 8;
    int c8 = (lane & 3) ^ ((lane >> 3) & 3);
    const unsigned short* bg = xt + ((size_t)b * TP + (t0 + 14 + (lane >> 2))) * C_ + c8 * 8;

    short8 af[2][8];
    short8 bf[4];

    // ---- prologue: stage chunk 0 into buffer 0, then tap0 -> af[0]
    {
        int c1 = 0;
#pragma unroll
        for (int f = wid; f < AFR; f += 8)
            gload_lds16(ag + (size_t)((f >> 3) * O_ + (f & 7) * 16) * C_, &a_lds[0][f * 512]);
#pragma unroll
        for (int j = wid; j < BGR; j += 8)
            gload_lds16(bg + (size_t)(j * 16) * C_, &b_lds[0][j * 512]);
        (void)c1;
    }
    asm volatile("s_waitcnt vmcnt(0)" ::: "memory");
    BARR;
    LDA(0, 0, 0);

#pragma unroll 1
    for (int cp = 0; cp < NCHUNK / 2; ++cp) {
        int ch = cp * 2;
        CHUNK_BODY(ch, 0);
        CHUNK_BODY(ch + 1, 1);
    }

    // ---- epilogue: C/D layout col=lane&15, row=(lane>>4)*4+reg
#pragma unroll
    for (int mi = 0; mi < 8; ++mi) {
#pragma unroll
        for (int ni = 0; ni < 4; ++ni) {
            int orow = o0 + mi * 16 + lg * 4;
            int tcol = t0 + wid * 64 + ni * 16 + lr;
#pragma unroll
            for (int r = 0; r < 4; ++r) {
                out[((size_t)b * O_ + orow + r) * T_ + tcol] =
                    acc[mi][ni][r] + bias[orow + r];
            }
        }
    }
}

extern "C" void kernel_launch(void* const* d_in, const int* in_sizes, int n_in,
                              void* d_out, int out_size, void* d_ws, size_t ws_size,
                              hipStream_t stream) {
    const float* x    = (const float*)d_in[0];
    const float* w    = (const float*)d_in[1];
    const float* bias = (const float*)d_in[2];
    float* out        = (float*)d_out;

    unsigned short* wb  = (unsigned short*)d_ws;            // 2.62 MB
    unsigned short* xtp = wb + (size_t)KT * O_ * C_;        // 16*4128*512 bf16 = 67.7 MB

    prep_kernel<<<6144, 256, 0, stream>>>(w, wb, xtp);
    xtrans_kernel<<<dim3(T_ / 64, C_ / 64, B_), 256, 0, stream>>>(x, xtp);
    conv_gemm_kernel<<<512, 512, 0, stream>>>(wb, xtp, bias, out);
}

// Round 13
// 202.765 us; speedup vs baseline: 1.2191x; 1.2191x over previous
//
#include <hip/hip_runtime.h>
#include <hip/hip_bf16.h>

typedef __attribute__((ext_vector_type(8))) short short8;
typedef __attribute__((ext_vector_type(16))) float f32x16;

#define B_   16
#define O_   512
#define C_   512
#define T_   4096
#define TP   (T_ + 32)     // padded t extent: 16 zero rows each side
#define KT   5
#define BM   128
#define BN   512
#define BK   32
#define NCHUNK (C_/BK)
#define AFR  40            // A fragments: 5 taps x 4 mtiles x 2 kslices, 1024B each
#define BGR  33            // B row-groups: 33 x 16 rows x 64B

__device__ __forceinline__ void gload_lds16(const void* g, void* l) {
    __builtin_amdgcn_global_load_lds(
        (const __attribute__((address_space(1))) unsigned int*)g,
        (__attribute__((address_space(3))) unsigned int*)l, 16, 0, 0);
}

// ---------------- fused prep: wrepack (blocks 0..5119) + padzero (5120..6143) ----
__global__ void prep_kernel(const float* __restrict__ w,
                            unsigned short* __restrict__ wb,
                            unsigned short* __restrict__ xt) {
    int bid = blockIdx.x;
    if (bid < 5120) {
        int e   = bid * 256 + threadIdx.x;
        int n   = e / (O_ * C_);
        int rem = e % (O_ * C_);
        int o   = rem / C_;
        int c   = rem % C_;
        float v = w[((size_t)o * C_ + c) * KT + n];
        __hip_bfloat16 h = __float2bfloat16(v);
        wb[e] = *reinterpret_cast<unsigned short*>(&h);
    } else {
        int i = (bid - 5120) * 256 + threadIdx.x;
        int b = i / (32 * C_);
        int r = (i / C_) % 32;
        int c = i % C_;
        int tp = (r < 16) ? r : (T_ + r);
        xt[((size_t)b * TP + tp) * C_ + c] = 0;
    }
}

// ---------------- x transpose: x[b][c][t] f32 -> xT[b][16+t][c] bf16 ----------------
__global__ void xtrans_kernel(const float* __restrict__ x, unsigned short* __restrict__ xt) {
    __shared__ float tile[64][65];
    int b  = blockIdx.z;
    int c0 = blockIdx.y * 64;
    int t0 = blockIdx.x * 64;
    const float* xb = x + ((size_t)b * C_ + c0) * T_ + t0;
#pragma unroll
    for (int p = 0; p < 4; ++p) {
        int idx = p * 256 + threadIdx.x;
        int cl = idx >> 4;
        int tj = (idx & 15) << 2;
        float4 v = *reinterpret_cast<const float4*>(xb + (size_t)cl * T_ + tj);
        tile[cl][tj + 0] = v.x;
        tile[cl][tj + 1] = v.y;
        tile[cl][tj + 2] = v.z;
        tile[cl][tj + 3] = v.w;
    }
    __syncthreads();
    unsigned short* xtb = xt + ((size_t)b * TP + 16 + t0) * C_ + c0;
#pragma unroll
    for (int p = 0; p < 2; ++p) {
        int g  = p * 256 + threadIdx.x;
        int tl = g >> 3;
        int cj = (g & 7) << 3;
        unsigned short tmp[8];
#pragma unroll
        for (int i = 0; i < 8; ++i) {
            __hip_bfloat16 h = __float2bfloat16(tile[cj + i][tl]);
            tmp[i] = *reinterpret_cast<unsigned short*>(&h);
        }
        *reinterpret_cast<short8*>(xtb + (size_t)tl * C_ + cj) =
            *reinterpret_cast<const short8*>(tmp);
    }
}

// ---------------- conv-as-GEMM, R9 phased pipeline, 32x32x16 MFMA ----------------
// Block tile 128(o) x 512(t), BK=32, 8 waves, wave tile 128x64 = 4m x 2n of 32x32.
// A: fragment-major LDS [tap][mt][ks], lane-linear 16B (zero-conflict, R6-verified
// operand mapping: row=lane&31, k=(lane>>5)*8+j).
// B: row-major [528][32], slot swizzle (row>>1)&3 (R4/R9-proven; balanced for
// 32-row spans since bank group depends only on row&1).
// Per chunk: 5 phases {8 A + 4 B ds_read; 1 A + <=1 B gload prefetch; s_barrier;
// 16 MFMA (compiler-counted lgkm waits)}. vmcnt(0) once per chunk end.
__global__ __launch_bounds__(512, 2) void conv_gemm_kernel(
        const unsigned short* __restrict__ wb,
        const unsigned short* __restrict__ xt,
        const float* __restrict__ bias,
        float* __restrict__ out) {
    __shared__ unsigned short a_lds[2][AFR * 512];   // 2 x 40960 B
    __shared__ unsigned short b_lds[2][BGR * 512];   // 2 x 33792 B

    // XCD-aware bijective swizzle (512 blocks): o-tile innermost.
    int bid = blockIdx.x;
    int swz = (bid & 7) * 64 + (bid >> 3);
    int o0  = (swz & 3) * BM;
    int t0  = ((swz >> 2) & 7) * BN;
    int b   = swz >> 5;

    int tid  = threadIdx.x;
    int lane = tid & 63;
    int wid  = tid >> 6;       // 0..7 = wave n-position
    int l31  = lane & 31;
    int lh   = lane >> 5;      // 0..1

    // chunk-invariant B read offsets (ushort units): row x 64B, slot = col8 ^ swz
    int bo[KT][2][2];
#pragma unroll
    for (int n = 0; n < KT; ++n)
#pragma unroll
        for (int ni = 0; ni < 2; ++ni)
#pragma unroll
            for (int ks = 0; ks < 2; ++ks) {
                int row = wid * 64 + ni * 32 + l31 + 4 - n;
                bo[n][ni][ks] = row * 32 + ((((ks << 1) + lh) ^ ((row >> 1) & 3)) << 3);
            }

    f32x16 acc[4][2];
#pragma unroll
    for (int mt = 0; mt < 4; ++mt)
#pragma unroll
        for (int ni = 0; ni < 2; ++ni)
            acc[mt][ni] = (f32x16)0.0f;

    // A staging: wave wid stages fragment (tap, mt=wid>>1, ks=wid&1) each phase;
    // per-lane source places element (row=l31, k=lh*8+j) lane-linear in LDS.
    const unsigned short* agb =
        wb + (size_t)(o0 + (wid >> 1) * 32 + l31) * C_ + (wid & 1) * 16 + lh * 8;
    // B staging: unchanged from R9 (same layout+swizzle).
    int c8 = (lane & 3) ^ ((lane >> 3) & 3);
    const unsigned short* bg = xt + ((size_t)b * TP + (t0 + 14 + (lane >> 2))) * C_ + c8 * 8;

    // ---- prologue: stage chunk 0 into buffer 0
#pragma unroll
    for (int f = wid; f < AFR; f += 8)
        gload_lds16(agb + (size_t)((f >> 3) * O_) * C_, &a_lds[0][f * 512]);
#pragma unroll
    for (int j = wid; j < BGR; j += 8)
        gload_lds16(bg + (size_t)(j * 16) * C_, &b_lds[0][j * 512]);
    asm volatile("s_waitcnt vmcnt(0)" ::: "memory");
    __builtin_amdgcn_s_barrier();

    for (int chunk = 0; chunk < NCHUNK; ++chunk) {
        int cur = chunk & 1;
        int c1  = (chunk + 1) * BK;
        bool pf = (chunk + 1 < NCHUNK);

#pragma unroll
        for (int n = 0; n < KT; ++n) {
            // ---- phase n: read tap n's fragments
            short8 af[4][2], bf[2][2];
#pragma unroll
            for (int mt = 0; mt < 4; ++mt)
#pragma unroll
                for (int ks = 0; ks < 2; ++ks)
                    af[mt][ks] = *reinterpret_cast<const short8*>(
                        &a_lds[cur][(n * 8 + mt * 2 + ks) * 512 + lane * 8]);
#pragma unroll
            for (int ni = 0; ni < 2; ++ni)
#pragma unroll
                for (int ks = 0; ks < 2; ++ks)
                    bf[ni][ks] = *reinterpret_cast<const short8*>(
                        &b_lds[cur][bo[n][ni][ks]]);

            // ---- prefetch slice for chunk+1 (1 A frag + <=1 B group per wave)
            if (pf) {
                gload_lds16(agb + (size_t)(n * O_) * C_ + c1,
                            &a_lds[cur ^ 1][(n * 8 + wid) * 512]);
                int j = n * 8 + wid;
                if (j < BGR)
                    gload_lds16(bg + (size_t)(j * 16) * C_ + c1, &b_lds[cur ^ 1][j * 512]);
            }

            __builtin_amdgcn_s_barrier();
            // no explicit lgkm drain: compiler emits counted lgkm waits (R9-proven).

            __builtin_amdgcn_s_setprio(1);
#pragma unroll
            for (int mt = 0; mt < 4; ++mt)
#pragma unroll
                for (int ni = 0; ni < 2; ++ni)
#pragma unroll
                    for (int ks = 0; ks < 2; ++ks)
                        acc[mt][ni] = __builtin_amdgcn_mfma_f32_32x32x16_bf16(
                            af[mt][ks], bf[ni][ks], acc[mt][ni], 0, 0, 0);
            __builtin_amdgcn_s_setprio(0);
        }

        // ---- chunk boundary: ensure next buffer fully staged on all waves
        asm volatile("s_waitcnt vmcnt(0)" ::: "memory");
        __builtin_amdgcn_s_barrier();
    }

    // ---- epilogue: 32x32 C/D layout col=lane&31, row=(r&3)+8*(r>>2)+4*lh (R6-verified)
#pragma unroll
    for (int mt = 0; mt < 4; ++mt) {
#pragma unroll
        for (int ni = 0; ni < 2; ++ni) {
            int tcol = t0 + wid * 64 + ni * 32 + l31;
#pragma unroll
            for (int r = 0; r < 16; ++r) {
                int orow = o0 + mt * 32 + (r & 3) + 8 * (r >> 2) + 4 * lh;
                out[((size_t)b * O_ + orow) * T_ + tcol] =
                    acc[mt][ni][r] + bias[orow];
            }
        }
    }
}

extern "C" void kernel_launch(void* const* d_in, const int* in_sizes, int n_in,
                              void* d_out, int out_size, void* d_ws, size_t ws_size,
                              hipStream_t stream) {
    const float* x    = (const float*)d_in[0];
    const float* w    = (const float*)d_in[1];
    const float* bias = (const float*)d_in[2];
    float* out        = (float*)d_out;

    unsigned short* wb  = (unsigned short*)d_ws;            // 2.62 MB
    unsigned short* xtp = wb + (size_t)KT * O_ * C_;        // 16*4128*512 bf16 = 67.7 MB

    prep_kernel<<<6144, 256, 0, stream>>>(w, wb, xtp);
    xtrans_kernel<<<dim3(T_ / 64, C_ / 64, B_), 256, 0, stream>>>(x, xtp);
    conv_gemm_kernel<<<512, 512, 0, stream>>>(wb, xtp, bias, out);
}